// Round 5
// baseline (1048.645 us; speedup 1.0000x reference)
//
#include <hip/hip_runtime.h>
#include <math.h>

// KGVAE: 2-layer RelGraphConv (bdd) + reparameterize, R5.
// Partial-product bdd edge loop (coalesced float4 weight loads, no per-edge
// shfl broadcast of x), butterfly transpose-reduce once per node, register+shfl
// self-loop GEMV (zero LDS), persistent blocks, launch_bounds for occupancy.
// ws: deg[N] | fil[N] | off[N+1] | h1[N*64] f32 | pack[E] u32 | norm_s[E] f32

__global__ void hist(const int* __restrict__ dst, int* __restrict__ deg, int e) {
    int i = blockIdx.x * blockDim.x + threadIdx.x;
    if (i < e) atomicAdd(&deg[dst[i]], 1);
}

__global__ void scan_deg(const int* __restrict__ deg, int* __restrict__ off, int n) {
    __shared__ int part[1024];
    int t = threadIdx.x;
    int chunk = (n + 1023) / 1024;
    int lo = t * chunk, hi = lo + chunk;
    if (hi > n) hi = n;
    int s = 0;
    for (int i = lo; i < hi; ++i) s += deg[i];
    part[t] = s;
    __syncthreads();
    for (int d = 1; d < 1024; d <<= 1) {
        int v = (t >= d) ? part[t - d] : 0;
        __syncthreads();
        part[t] += v;
        __syncthreads();
    }
    int run = part[t] - s;
    for (int i = lo; i < hi; ++i) { off[i] = run; run += deg[i]; }
    if (t == 1023) off[n] = part[1023];
}

__global__ void scatter_pack(const int* __restrict__ src, const int* __restrict__ dst,
                             const int* __restrict__ rel, const float* __restrict__ norm,
                             const int* __restrict__ off, int* __restrict__ fil,
                             unsigned int* __restrict__ pack, float* __restrict__ norm_s,
                             int e) {
    int i = blockIdx.x * blockDim.x + threadIdx.x;
    if (i >= e) return;
    int d = dst[i];
    int p = off[d] + atomicAdd(&fil[d], 1);
    pack[p] = (unsigned)src[i] | ((unsigned)rel[i] << 16);
    norm_s[p] = norm[i];
}

// butterfly transpose-reduce over 8-lane group: lane with sub-index i ends
// with sum over the group of a[i]
__device__ __forceinline__ float reduce8(float a0, float a1, float a2, float a3,
                                         float a4, float a5, float a6, float a7, int i) {
    int p1 = i & 1, p2 = (i >> 1) & 1, p3 = (i >> 2) & 1;
    float ka, sb, u0, u1, u2, u3, w0, w1;
    ka = p1 ? a1 : a0; sb = p1 ? a0 : a1; u0 = ka + __shfl_xor(sb, 1, 64);
    ka = p1 ? a3 : a2; sb = p1 ? a2 : a3; u1 = ka + __shfl_xor(sb, 1, 64);
    ka = p1 ? a5 : a4; sb = p1 ? a4 : a5; u2 = ka + __shfl_xor(sb, 1, 64);
    ka = p1 ? a7 : a6; sb = p1 ? a6 : a7; u3 = ka + __shfl_xor(sb, 1, 64);
    ka = p2 ? u1 : u0; sb = p2 ? u0 : u1; w0 = ka + __shfl_xor(sb, 2, 64);
    ka = p2 ? u3 : u2; sb = p2 ? u2 : u3; w1 = ka + __shfl_xor(sb, 2, 64);
    ka = p3 ? w1 : w0; sb = p3 ? w0 : w1;
    return ka + __shfl_xor(sb, 4, 64);
}

// layer1: h1[n] = b1 + feat[n]@lw1 + sum_e nm*bdd(feat[src], w1[rel])
__global__ __launch_bounds__(256, 8) void
layer1(const float* __restrict__ emb, const int* __restrict__ h_ids,
       const float* __restrict__ w1, const float* __restrict__ lw1,
       const float* __restrict__ b1, const int* __restrict__ off,
       const unsigned* __restrict__ pack, const float* __restrict__ norm_s,
       float* __restrict__ h1, int n_nodes) {
    int tid = threadIdx.x;
    int w = tid >> 6, j = tid & 63;
    int i = j & 7;
    int stride = gridDim.x * 4;
    for (int n = blockIdx.x * 4 + w; n < n_nodes; n += stride) {
        float xv = emb[(long)h_ids[n] * 64 + j];
        // edge aggregation: lane j=(b,i) accumulates partials for o=0..7
        float a0 = 0.f, a1 = 0.f, a2 = 0.f, a3 = 0.f, a4 = 0.f, a5 = 0.f, a6 = 0.f, a7 = 0.f;
        int e0 = off[n], e1 = off[n + 1];
        long woff = (long)j * 8;  // b*64 + i*8
        for (int win = e0; win < e1; win += 64) {
            int wcnt = e1 - win; if (wcnt > 64) wcnt = 64;
            unsigned u = (j < wcnt) ? pack[win + j] : 0u;
            float nmv = (j < wcnt) ? norm_s[win + j] : 0.f;
            int hv = (j < wcnt) ? h_ids[u & 0xFFFFu] : 0;
            int rv = (int)(u >> 16);
            for (int base = 0; base < wcnt; base += 8) {
                int cnt = wcnt - base; if (cnt > 8) cnt = 8;
                float xs[8];
#pragma unroll
                for (int c = 0; c < 8; ++c)
                    if (c < cnt) xs[c] = emb[(long)__shfl(hv, base + c, 64) * 64 + j];
#pragma unroll
                for (int c = 0; c < 8; ++c)
                    if (c < cnt) {
                        int r = __shfl(rv, base + c, 64);
                        float nm = __shfl(nmv, base + c, 64);
                        float xm = xs[c] * nm;
                        const float4* w4 = (const float4*)(w1 + (long)r * 512 + woff);
                        float4 wa = w4[0], wb = w4[1];
                        a0 = fmaf(xm, wa.x, a0); a1 = fmaf(xm, wa.y, a1);
                        a2 = fmaf(xm, wa.z, a2); a3 = fmaf(xm, wa.w, a3);
                        a4 = fmaf(xm, wb.x, a4); a5 = fmaf(xm, wb.y, a5);
                        a6 = fmaf(xm, wb.z, a6); a7 = fmaf(xm, wb.w, a7);
                    }
            }
        }
        float agg = reduce8(a0, a1, a2, a3, a4, a5, a6, a7, i);
        // self-loop GEMV: lane j -> output column j, x broadcast via shfl
        float sacc = b1[j];
#pragma unroll
        for (int k = 0; k < 64; ++k)
            sacc = fmaf(__shfl(xv, k, 64), lw1[k * 64 + j], sacc);
        h1[(long)n * 64 + j] = sacc + agg;
    }
}

// layer2: h2 = b2 + relu(h1[n])@lw2 + sum_e nm*bdd(relu(h1[src]), w2[rel]); fused reparam
__global__ __launch_bounds__(256, 6) void
layer2(const float* __restrict__ h1, const float* __restrict__ w2,
       const float* __restrict__ lw2, const float* __restrict__ b2,
       const float* __restrict__ eps, const int* __restrict__ off,
       const unsigned* __restrict__ pack, const float* __restrict__ norm_s,
       float* __restrict__ out, int n_nodes) {
    int tid = threadIdx.x;
    int w = tid >> 6, j = tid & 63;
    int i = j & 7, b = j >> 3;
    int o1 = b * 16 + i, o2 = o1 + 8;
    int stride = gridDim.x * 4;
    for (int n = blockIdx.x * 4 + w; n < n_nodes; n += stride) {
        float xv = fmaxf(h1[(long)n * 64 + j], 0.f);
        float a[16];
#pragma unroll
        for (int q = 0; q < 16; ++q) a[q] = 0.f;
        int e0 = off[n], e1 = off[n + 1];
        long woff = (long)b * 128 + i * 16;
        for (int win = e0; win < e1; win += 64) {
            int wcnt = e1 - win; if (wcnt > 64) wcnt = 64;
            unsigned u = (j < wcnt) ? pack[win + j] : 0u;
            float nmv = (j < wcnt) ? norm_s[win + j] : 0.f;
            int sv = (int)(u & 0xFFFFu);
            int rv = (int)(u >> 16);
            for (int base = 0; base < wcnt; base += 8) {
                int cnt = wcnt - base; if (cnt > 8) cnt = 8;
                float xs[8];
#pragma unroll
                for (int c = 0; c < 8; ++c)
                    if (c < cnt) xs[c] = fmaxf(h1[(long)__shfl(sv, base + c, 64) * 64 + j], 0.f);
#pragma unroll
                for (int c = 0; c < 8; ++c)
                    if (c < cnt) {
                        int r = __shfl(rv, base + c, 64);
                        float nm = __shfl(nmv, base + c, 64);
                        float xm = xs[c] * nm;
                        const float4* w4 = (const float4*)(w2 + (long)r * 1024 + woff);
                        float4 wa = w4[0], wb = w4[1], wc = w4[2], wd = w4[3];
                        a[0] = fmaf(xm, wa.x, a[0]);  a[1] = fmaf(xm, wa.y, a[1]);
                        a[2] = fmaf(xm, wa.z, a[2]);  a[3] = fmaf(xm, wa.w, a[3]);
                        a[4] = fmaf(xm, wb.x, a[4]);  a[5] = fmaf(xm, wb.y, a[5]);
                        a[6] = fmaf(xm, wb.z, a[6]);  a[7] = fmaf(xm, wb.w, a[7]);
                        a[8] = fmaf(xm, wc.x, a[8]);  a[9] = fmaf(xm, wc.y, a[9]);
                        a[10] = fmaf(xm, wc.z, a[10]); a[11] = fmaf(xm, wc.w, a[11]);
                        a[12] = fmaf(xm, wd.x, a[12]); a[13] = fmaf(xm, wd.y, a[13]);
                        a[14] = fmaf(xm, wd.z, a[14]); a[15] = fmaf(xm, wd.w, a[15]);
                    }
            }
        }
        float r1 = reduce8(a[0], a[1], a[2], a[3], a[4], a[5], a[6], a[7], i);       // h2[b*16+i]
        float r2 = reduce8(a[8], a[9], a[10], a[11], a[12], a[13], a[14], a[15], i); // h2[b*16+8+i]
        // self-loop GEMV for columns o1, o2; x broadcast via shfl
        float sA = b2[o1], sB = b2[o2];
#pragma unroll
        for (int k = 0; k < 64; ++k) {
            float xk = __shfl(xv, k, 64);
            sA = fmaf(xk, lw2[k * 128 + o1], sA);
            sB = fmaf(xk, lw2[k * 128 + o2], sB);
        }
        float v1 = r1 + sA;  // h2[n, o1]
        float v2 = r2 + sB;  // h2[n, o2]
        // pair m (cols<64, lanes b<4) with raw_v (cols>=64, lanes b>=4)
        float p1 = __shfl_xor(v1, 32, 64);
        float p2 = __shfl_xor(v2, 32, 64);
        if (j < 32) {
            long base = (long)n * 64;
            float sp1 = (p1 > 20.f) ? p1 : log1pf(expf(p1));
            float sp2 = (p2 > 20.f) ? p2 : log1pf(expf(p2));
            out[base + o1] = fmaf(sqrtf(sp1 + 1e-8f), eps[base + o1], v1);
            out[base + o2] = fmaf(sqrtf(sp2 + 1e-8f), eps[base + o2], v2);
        }
    }
}

extern "C" void kernel_launch(void* const* d_in, const int* in_sizes, int n_in,
                              void* d_out, int out_size, void* d_ws, size_t ws_size,
                              hipStream_t stream) {
    const float* emb   = (const float*)d_in[0];
    const float* norm  = (const float*)d_in[1];
    const float* eps   = (const float*)d_in[2];
    const float* w1    = (const float*)d_in[3];
    const float* lw1   = (const float*)d_in[4];
    const float* b1    = (const float*)d_in[5];
    const float* w2    = (const float*)d_in[6];
    const float* lw2   = (const float*)d_in[7];
    const float* b2    = (const float*)d_in[8];
    const int*   h_ids = (const int*)d_in[9];
    const int*   src   = (const int*)d_in[10];
    const int*   dst   = (const int*)d_in[11];
    const int*   rel   = (const int*)d_in[12];
    float* out = (float*)d_out;

    int n_nodes = in_sizes[0] / 64;   // 50000
    int n_edges = in_sizes[10];       // 400000

    char* ws = (char*)d_ws;
    int*   deg    = (int*)ws;                         ws += (size_t)n_nodes * 4;
    int*   fil    = (int*)ws;                         ws += (size_t)n_nodes * 4;
    int*   off    = (int*)ws;                         ws += (size_t)(n_nodes + 1) * 4;
    float* h1     = (float*)ws;                       ws += (size_t)n_nodes * 64 * 4;
    unsigned* pk  = (unsigned*)ws;                    ws += (size_t)n_edges * 4;
    float* norm_s = (float*)ws;

    int blk = 256;
    hipMemsetAsync(deg, 0, (size_t)n_nodes * 8, stream);
    hist<<<(n_edges + blk - 1) / blk, blk, 0, stream>>>(dst, deg, n_edges);
    scan_deg<<<1, 1024, 0, stream>>>(deg, off, n_nodes);
    scatter_pack<<<(n_edges + blk - 1) / blk, blk, 0, stream>>>(src, dst, rel, norm, off, fil, pk, norm_s, n_edges);
    layer1<<<2048, blk, 0, stream>>>(emb, h_ids, w1, lw1, b1, off, pk, norm_s, h1, n_nodes);
    layer2<<<2048, blk, 0, stream>>>(h1, w2, lw2, b2, eps, off, pk, norm_s, out, n_nodes);
}

// Round 6
// 430.756 us; speedup vs baseline: 2.4344x; 2.4344x over previous
//
#include <hip/hip_runtime.h>
#include <math.h>

// KGVAE: 2-layer RelGraphConv (bdd) + reparameterize, R6.
// Partial-product bdd edge loop; ALL cross-lane broadcasts via readlane
// (scalar pipe, wave-uniform index) -> SGPR-base coalesced gathers; h_ids
// folded at pack time; zero LDS; launch_bounds(256,4) so nothing spills.
// ws: deg[N] | fil[N] | off[N+1] | h1[N*64] | packA[E] | packB[E] | norm_s[E]

__device__ __forceinline__ int bcasti(int v, int l) {
    return __builtin_amdgcn_readlane(v, l);
}
__device__ __forceinline__ float bcastf(float v, int l) {
    return __int_as_float(__builtin_amdgcn_readlane(__float_as_int(v), l));
}

__global__ void hist(const int* __restrict__ dst, int* __restrict__ deg, int e) {
    int i = blockIdx.x * blockDim.x + threadIdx.x;
    if (i < e) atomicAdd(&deg[dst[i]], 1);
}

__global__ void scan_deg(const int* __restrict__ deg, int* __restrict__ off, int n) {
    __shared__ int part[1024];
    int t = threadIdx.x;
    int chunk = (n + 1023) / 1024;
    int lo = t * chunk, hi = lo + chunk;
    if (hi > n) hi = n;
    int s = 0;
    for (int i = lo; i < hi; ++i) s += deg[i];
    part[t] = s;
    __syncthreads();
    for (int d = 1; d < 1024; d <<= 1) {
        int v = (t >= d) ? part[t - d] : 0;
        __syncthreads();
        part[t] += v;
        __syncthreads();
    }
    int run = part[t] - s;
    for (int i = lo; i < hi; ++i) { off[i] = run; run += deg[i]; }
    if (t == 1023) off[n] = part[1023];
}

// packA = h_ids[src] | rel<<16  (layer1 gathers emb);  packB = src | rel<<16 (layer2 gathers h1)
__global__ void scatter_pack(const int* __restrict__ src, const int* __restrict__ dst,
                             const int* __restrict__ rel, const float* __restrict__ norm,
                             const int* __restrict__ h_ids, const int* __restrict__ off,
                             int* __restrict__ fil, unsigned* __restrict__ packA,
                             unsigned* __restrict__ packB, float* __restrict__ norm_s, int e) {
    int i = blockIdx.x * blockDim.x + threadIdx.x;
    if (i >= e) return;
    int d = dst[i];
    int p = off[d] + atomicAdd(&fil[d], 1);
    unsigned rhi = (unsigned)rel[i] << 16;
    int s = src[i];
    packA[p] = (unsigned)h_ids[s] | rhi;
    packB[p] = (unsigned)s | rhi;
    norm_s[p] = norm[i];
}

// butterfly transpose-reduce over 8-lane group: lane with sub-index i ends
// with sum over the group of a[i]
__device__ __forceinline__ float reduce8(float a0, float a1, float a2, float a3,
                                         float a4, float a5, float a6, float a7, int i) {
    int p1 = i & 1, p2 = (i >> 1) & 1, p3 = (i >> 2) & 1;
    float ka, sb, u0, u1, u2, u3, w0, w1;
    ka = p1 ? a1 : a0; sb = p1 ? a0 : a1; u0 = ka + __shfl_xor(sb, 1, 64);
    ka = p1 ? a3 : a2; sb = p1 ? a2 : a3; u1 = ka + __shfl_xor(sb, 1, 64);
    ka = p1 ? a5 : a4; sb = p1 ? a4 : a5; u2 = ka + __shfl_xor(sb, 1, 64);
    ka = p1 ? a7 : a6; sb = p1 ? a6 : a7; u3 = ka + __shfl_xor(sb, 1, 64);
    ka = p2 ? u1 : u0; sb = p2 ? u0 : u1; w0 = ka + __shfl_xor(sb, 2, 64);
    ka = p2 ? u3 : u2; sb = p2 ? u2 : u3; w1 = ka + __shfl_xor(sb, 2, 64);
    ka = p3 ? w1 : w0; sb = p3 ? w0 : w1;
    return ka + __shfl_xor(sb, 4, 64);
}

// layer1: h1[n] = b1 + feat[n]@lw1 + sum_e nm*bdd(feat[src], w1[rel])
__global__ __launch_bounds__(256, 4) void
layer1(const float* __restrict__ emb, const int* __restrict__ h_ids,
       const float* __restrict__ w1, const float* __restrict__ lw1,
       const float* __restrict__ b1, const int* __restrict__ off,
       const unsigned* __restrict__ packA, const float* __restrict__ norm_s,
       float* __restrict__ h1, int n_nodes) {
    int tid = threadIdx.x;
    int w = tid >> 6, j = tid & 63, i = j & 7;
    int n = blockIdx.x * 4 + w;
    if (n >= n_nodes) return;
    float xv = emb[(long)h_ids[n] * 64 + j];
    float a0 = 0.f, a1 = 0.f, a2 = 0.f, a3 = 0.f, a4 = 0.f, a5 = 0.f, a6 = 0.f, a7 = 0.f;
    int e0 = off[n], e1 = off[n + 1];
    const long woff = (long)j * 8;  // b*64 + i*8
    for (int win = e0; win < e1; win += 64) {
        int wcnt = e1 - win; if (wcnt > 64) wcnt = 64;
        unsigned u = (j < wcnt) ? packA[win + j] : 0u;
        float nmv = (j < wcnt) ? norm_s[win + j] : 0.f;
        for (int base = 0; base < wcnt; base += 8) {
            int cnt = wcnt - base; if (cnt > 8) cnt = 8;
            float xs[8];
            int rr[8];
#pragma unroll
            for (int c = 0; c < 8; ++c)
                if (c < cnt) {
                    int uc = bcasti((int)u, base + c);          // SGPR broadcast
                    xs[c] = emb[(long)(uc & 0xFFFF) * 64 + j];  // coalesced 256B gather
                    rr[c] = uc >> 16;
                }
#pragma unroll
            for (int c = 0; c < 8; ++c)
                if (c < cnt) {
                    float nm = bcastf(nmv, base + c);
                    const float4* w4 = (const float4*)(w1 + (long)rr[c] * 512 + woff);
                    float4 wa = w4[0], wb = w4[1];
                    float xm = xs[c] * nm;
                    a0 = fmaf(xm, wa.x, a0); a1 = fmaf(xm, wa.y, a1);
                    a2 = fmaf(xm, wa.z, a2); a3 = fmaf(xm, wa.w, a3);
                    a4 = fmaf(xm, wb.x, a4); a5 = fmaf(xm, wb.y, a5);
                    a6 = fmaf(xm, wb.z, a6); a7 = fmaf(xm, wb.w, a7);
                }
        }
    }
    float agg = reduce8(a0, a1, a2, a3, a4, a5, a6, a7, i);
    // self-loop GEMV: lane j -> output col j; x broadcast via readlane
    float sacc = b1[j];
#pragma unroll 16
    for (int k = 0; k < 64; ++k)
        sacc = fmaf(bcastf(xv, k), lw1[k * 64 + j], sacc);
    h1[(long)n * 64 + j] = sacc + agg;
}

// layer2: h2 = b2 + relu(h1[n])@lw2 + sum_e nm*bdd(relu(h1[src]), w2[rel]); fused reparam
__global__ __launch_bounds__(256, 4) void
layer2(const float* __restrict__ h1, const float* __restrict__ w2,
       const float* __restrict__ lw2, const float* __restrict__ b2,
       const float* __restrict__ eps, const int* __restrict__ off,
       const unsigned* __restrict__ packB, const float* __restrict__ norm_s,
       float* __restrict__ out, int n_nodes) {
    int tid = threadIdx.x;
    int w = tid >> 6, j = tid & 63;
    int i = j & 7, b = j >> 3;
    int o1 = b * 16 + i, o2 = o1 + 8;
    int n = blockIdx.x * 4 + w;
    if (n >= n_nodes) return;
    float xv = fmaxf(h1[(long)n * 64 + j], 0.f);
    float a[16];
#pragma unroll
    for (int q = 0; q < 16; ++q) a[q] = 0.f;
    int e0 = off[n], e1 = off[n + 1];
    const long woff = (long)j * 16;  // b*128 + i*16
    for (int win = e0; win < e1; win += 64) {
        int wcnt = e1 - win; if (wcnt > 64) wcnt = 64;
        unsigned u = (j < wcnt) ? packB[win + j] : 0u;
        float nmv = (j < wcnt) ? norm_s[win + j] : 0.f;
        for (int base = 0; base < wcnt; base += 8) {
            int cnt = wcnt - base; if (cnt > 8) cnt = 8;
            float xs[8];
            int rr[8];
#pragma unroll
            for (int c = 0; c < 8; ++c)
                if (c < cnt) {
                    int uc = bcasti((int)u, base + c);
                    xs[c] = fmaxf(h1[(long)(uc & 0xFFFF) * 64 + j], 0.f);
                    rr[c] = uc >> 16;
                }
#pragma unroll
            for (int c = 0; c < 8; ++c)
                if (c < cnt) {
                    float nm = bcastf(nmv, base + c);
                    const float4* w4 = (const float4*)(w2 + (long)rr[c] * 1024 + woff);
                    float4 wa = w4[0], wb = w4[1], wc = w4[2], wd = w4[3];
                    float xm = xs[c] * nm;
                    a[0] = fmaf(xm, wa.x, a[0]);   a[1] = fmaf(xm, wa.y, a[1]);
                    a[2] = fmaf(xm, wa.z, a[2]);   a[3] = fmaf(xm, wa.w, a[3]);
                    a[4] = fmaf(xm, wb.x, a[4]);   a[5] = fmaf(xm, wb.y, a[5]);
                    a[6] = fmaf(xm, wb.z, a[6]);   a[7] = fmaf(xm, wb.w, a[7]);
                    a[8] = fmaf(xm, wc.x, a[8]);   a[9] = fmaf(xm, wc.y, a[9]);
                    a[10] = fmaf(xm, wc.z, a[10]); a[11] = fmaf(xm, wc.w, a[11]);
                    a[12] = fmaf(xm, wd.x, a[12]); a[13] = fmaf(xm, wd.y, a[13]);
                    a[14] = fmaf(xm, wd.z, a[14]); a[15] = fmaf(xm, wd.w, a[15]);
                }
        }
    }
    float r1 = reduce8(a[0], a[1], a[2], a[3], a[4], a[5], a[6], a[7], i);        // col b*16+i
    float r2 = reduce8(a[8], a[9], a[10], a[11], a[12], a[13], a[14], a[15], i);  // col b*16+8+i
    // self-loop GEMV for cols o1,o2; x broadcast via readlane
    float sA = b2[o1], sB = b2[o2];
#pragma unroll 8
    for (int k = 0; k < 64; ++k) {
        float xk = bcastf(xv, k);
        sA = fmaf(xk, lw2[k * 128 + o1], sA);
        sB = fmaf(xk, lw2[k * 128 + o2], sB);
    }
    float v1 = r1 + sA;  // h2[n, o1]
    float v2 = r2 + sB;  // h2[n, o2]
    // pair m (cols<64, lanes b<4) with raw_v (cols>=64): partner lane j^32
    float p1 = __shfl_xor(v1, 32, 64);
    float p2 = __shfl_xor(v2, 32, 64);
    if (j < 32) {
        long basep = (long)n * 64;
        float sp1 = (p1 > 20.f) ? p1 : log1pf(expf(p1));
        float sp2 = (p2 > 20.f) ? p2 : log1pf(expf(p2));
        out[basep + o1] = fmaf(sqrtf(sp1 + 1e-8f), eps[basep + o1], v1);
        out[basep + o2] = fmaf(sqrtf(sp2 + 1e-8f), eps[basep + o2], v2);
    }
}

extern "C" void kernel_launch(void* const* d_in, const int* in_sizes, int n_in,
                              void* d_out, int out_size, void* d_ws, size_t ws_size,
                              hipStream_t stream) {
    const float* emb   = (const float*)d_in[0];
    const float* norm  = (const float*)d_in[1];
    const float* eps   = (const float*)d_in[2];
    const float* w1    = (const float*)d_in[3];
    const float* lw1   = (const float*)d_in[4];
    const float* b1    = (const float*)d_in[5];
    const float* w2    = (const float*)d_in[6];
    const float* lw2   = (const float*)d_in[7];
    const float* b2    = (const float*)d_in[8];
    const int*   h_ids = (const int*)d_in[9];
    const int*   src   = (const int*)d_in[10];
    const int*   dst   = (const int*)d_in[11];
    const int*   rel   = (const int*)d_in[12];
    float* out = (float*)d_out;

    int n_nodes = in_sizes[0] / 64;   // 50000
    int n_edges = in_sizes[10];       // 400000

    char* ws = (char*)d_ws;
    int*   deg    = (int*)ws;                         ws += (size_t)n_nodes * 4;
    int*   fil    = (int*)ws;                         ws += (size_t)n_nodes * 4;
    int*   off    = (int*)ws;                         ws += (size_t)(n_nodes + 1) * 4;
    float* h1     = (float*)ws;                       ws += (size_t)n_nodes * 64 * 4;
    unsigned* pkA = (unsigned*)ws;                    ws += (size_t)n_edges * 4;
    unsigned* pkB = (unsigned*)ws;                    ws += (size_t)n_edges * 4;
    float* norm_s = (float*)ws;

    int blk = 256;
    hipMemsetAsync(deg, 0, (size_t)n_nodes * 8, stream);
    hist<<<(n_edges + blk - 1) / blk, blk, 0, stream>>>(dst, deg, n_edges);
    scan_deg<<<1, 1024, 0, stream>>>(deg, off, n_nodes);
    scatter_pack<<<(n_edges + blk - 1) / blk, blk, 0, stream>>>(src, dst, rel, norm, h_ids, off, fil, pkA, pkB, norm_s, n_edges);
    int grid = (n_nodes + 3) / 4;
    layer1<<<grid, blk, 0, stream>>>(emb, h_ids, w1, lw1, b1, off, pkA, norm_s, h1, n_nodes);
    layer2<<<grid, blk, 0, stream>>>(h1, w2, lw2, b2, eps, off, pkB, norm_s, out, n_nodes);
}